// Round 17
// baseline (238.542 us; speedup 1.0000x reference)
//
#include <hip/hip_runtime.h>
#include <cstdint>
#include <cstddef>

// ---- types ----
typedef unsigned short u16;
typedef float  f32x4  __attribute__((ext_vector_type(4)));
typedef __bf16 bf16x8 __attribute__((ext_vector_type(8)));
typedef unsigned short us8 __attribute__((ext_vector_type(8)));
typedef unsigned short us4 __attribute__((ext_vector_type(4)));
typedef float  f32x4v __attribute__((ext_vector_type(4)));
typedef unsigned int u32x2 __attribute__((ext_vector_type(2)));

#define AS1 __attribute__((address_space(1)))
#define AS3 __attribute__((address_space(3)))

// fp32 -> bf16 round-to-nearest-even (scalar)
__device__ __forceinline__ u16 f2b(float f) {
  unsigned u = __float_as_uint(f);
  u += 0x7FFFu + ((u >> 16) & 1u);
  return (u16)(u >> 16);
}

// pack two fp32 -> bf16x2 dword (round-half-up; a = low 16, b = high 16)
__device__ __forceinline__ unsigned pkbf(float a, float b) {
  unsigned ua = __float_as_uint(a) + 0x8000u;
  unsigned ub = __float_as_uint(b) + 0x8000u;
  return __builtin_amdgcn_perm(ub, ua, 0x07060302u);
}

// pack two fp32 -> bf16x2 via casts (compiler emits v_cvt_pk_bf16_f32, RNE)
__device__ __forceinline__ unsigned cvtpk(float a, float b) {
  unsigned short lo = __builtin_bit_cast(unsigned short, (__bf16)a);
  unsigned short hi = __builtin_bit_cast(unsigned short, (__bf16)b);
  return (unsigned)lo | ((unsigned)hi << 16);
}

__device__ __forceinline__ bf16x8 ldfrag(const u16* p) {
  us8 v = *(const us8*)p;
  return __builtin_bit_cast(bf16x8, v);
}

__device__ __forceinline__ f32x4 mfma16(bf16x8 a, bf16x8 b, f32x4 c) {
  return __builtin_amdgcn_mfma_f32_16x16x32_bf16(a, b, c, 0, 0, 0);
}

// async global->LDS, 16B per lane; lds base must be wave-uniform (lane*16 auto-added)
__device__ __forceinline__ void gl_lds16(const u16* g, AS3 u16* l) {
  __builtin_amdgcn_global_load_lds((AS1 void*)g, (AS3 void*)l, 16, 0, 0);
}

// R13 BK=64 LDS layout (gemm_qkv — proven conflict-free): rows of 64 u16 =
// eight 16B granules; row stride 128B. LDS[r][p] = global[r][g], p = g^(r&7).
// Staging source granule g = (lane&7)^(lane>>3); reader pos = (kk*4+quad)^
// (l16&7). Measured 0 bank conflicts.
// R22 BK=128 layout (kept in gemm_out only, under test): 16-granule rows,
// p = g^(r&7) on low-3 bits. In gemm_qkv this layout measured 6.29e6
// conflicts (pos/pos+8 same-bank aliasing) and +7us -> REVERTED there.
// R23 decomposition: {qkv: BK=64} + {out: BK=128} isolates gemm_out-128 vs
// R21 {64,64}=235.9 and R22 {128,128}=233.9.

// ---- fused cast: x + all 4 weights. grid-stride, 3072 blocks x 4 iters ----
__global__ __launch_bounds__(256) void cvt_all(
    const float* __restrict__ x,
    const float* __restrict__ Wq, const float* __restrict__ Wk,
    const float* __restrict__ Wv, const float* __restrict__ Wo,
    u16* __restrict__ xb, u16* __restrict__ Wqkv, u16* __restrict__ Wob) {
  for (int blk = blockIdx.x; blk < 12288; blk += 3072) {
    const float* s;
    u16* d;
    int i;
    if (blk < 8192)       { s = x;  d = xb;             i = blk * 256 + threadIdx.x; }
    else if (blk < 9216)  { s = Wq; d = Wqkv;           i = (blk - 8192) * 256 + threadIdx.x; }
    else if (blk < 10240) { s = Wk; d = Wqkv + 1048576; i = (blk - 9216) * 256 + threadIdx.x; }
    else if (blk < 11264) { s = Wv; d = Wqkv + 2097152; i = (blk - 10240) * 256 + threadIdx.x; }
    else                  { s = Wo; d = Wob;            i = (blk - 11264) * 256 + threadIdx.x; }
    f32x4v f = ((const f32x4v*)s)[i];
    us4 o = { f2b(f[0]), f2b(f[1]), f2b(f[2]), f2b(f[3]) };
    ((us4*)d)[i] = o;
  }
}

// ---- GEMM1: C = X @ Wqkv^T -> Q (prescaled by 0.125*log2e), K, Vt.
// 128x128 tile, 256 threads, BK=64 (R13 — reverted from R22's BK=128 which
// added 6.29e6 bank conflicts and +7us), per-section MFMA orientation +
// 8B packed epilogue (R12), persistent 512-block grid + same-A sec fusion +
// 1-D XCD chunk (R15). Serial-stage 2-barrier K-loop (best: 68.6 us).
__global__ __launch_bounds__(256) void gemm_qkv(
    const u16* __restrict__ A, const u16* __restrict__ W,
    u16* __restrict__ Qb, u16* __restrict__ Kb, u16* __restrict__ Vt) {
  __shared__ u16 lA[128 * 64];   // 16 KB
  __shared__ u16 lB[128 * 64];   // 16 KB
  const int tid = threadIdx.x;
  const int lane = tid & 63, wave = tid >> 6;
  const int quad = lane >> 4, l16 = lane & 15;
  const int wr = wave >> 1, wc = wave & 1;

  const int p = blockIdx.x;
  const int l = (p & 7) * 64 + (p >> 3);   // XCD-chunk swizzle (bijective)
  const int by = l >> 3;
  const int bx0 = l & 7;
  const int m0 = by * 128;

  AS3 u16* lA3 = (AS3 u16*)lA;
  AS3 u16* lB3 = (AS3 u16*)lB;
  const int g3 = (((lane & 7) ^ (lane >> 3)) * 8);   // staging source granule col
  const int srow = lane >> 3;                        // 0..7 within 8-row group
  const int pA = ((quad) ^ (l16 & 7)) * 8;           // reader pos, kk=0
  const int pB = ((4 + quad) ^ (l16 & 7)) * 8;       // reader pos, kk=1

  const u16* gA = A + (size_t)(m0 + wave * 8 + srow) * 1024 + g3;

#pragma unroll 1
  for (int sec = 0; sec < 3; sec++) {    // tile bx = bx0 + sec*8; sec: 0=Q 1=K 2=V
    const int n0 = (bx0 + sec * 8) * 128;
    const u16* gB = W + (size_t)(n0 + wave * 8 + srow) * 1024 + g3;
    f32x4 acc[4][4] = {};

    for (int k0 = 0; k0 < 1024; k0 += 64) {
      __syncthreads();
#pragma unroll
      for (int i = 0; i < 4; i++) {   // instruction j = i*4+wave stages rows j*8..j*8+7
        gl_lds16(gA + (size_t)i * 32768 + k0, lA3 + (i * 4 + wave) * 512);
        gl_lds16(gB + (size_t)i * 32768 + k0, lB3 + (i * 4 + wave) * 512);
      }
      __syncthreads();
#pragma unroll
      for (int kk = 0; kk < 2; kk++) {
        const int pk = kk ? pB : pA;
        bf16x8 aF[4], bF[4];
#pragma unroll
        for (int mt = 0; mt < 4; mt++)
          aF[mt] = ldfrag(&lA[(wr * 64 + mt * 16 + l16) * 64 + pk]);
#pragma unroll
        for (int nt = 0; nt < 4; nt++)
          bF[nt] = ldfrag(&lB[(wc * 64 + nt * 16 + l16) * 64 + pk]);
        if (sec != 2) {  // SWAPPED: D[row=feature n, col=token m]
#pragma unroll
          for (int mt = 0; mt < 4; mt++)
#pragma unroll
            for (int nt = 0; nt < 4; nt++)
              acc[mt][nt] = mfma16(bF[nt], aF[mt], acc[mt][nt]);
        } else {         // NON-swapped: D[row=token m, col=feature n]
#pragma unroll
          for (int mt = 0; mt < 4; mt++)
#pragma unroll
            for (int nt = 0; nt < 4; nt++)
              acc[mt][nt] = mfma16(aF[mt], bF[nt], acc[mt][nt]);
        }
      }
    }

    if (sec != 2) {
      // Q/K: regs walk e; lane l16 = token. 8B store per (mt,nt).
      const float qsc = (sec == 0) ? 0.180336880111120426f : 1.0f;  // 0.125*log2e
      u16* __restrict__ D = (sec == 0) ? Qb : Kb;
      const int hb = ((n0 & 1023) >> 6) + wc;  // head (uniform per wave-col)
#pragma unroll
      for (int mt = 0; mt < 4; mt++) {
        int t = m0 + wr * 64 + mt * 16 + l16;
        int b = t >> 11, tt = t & 2047;
        size_t rowb = (((size_t)b * 16 + hb) * 2048 + tt) * 64;
#pragma unroll
        for (int nt = 0; nt < 4; nt++) {
          int e = nt * 16 + quad * 4;
          u32x2 pk = { pkbf(acc[mt][nt][0] * qsc, acc[mt][nt][1] * qsc),
                       pkbf(acc[mt][nt][2] * qsc, acc[mt][nt][3] * qsc) };
          *(u32x2*)&D[rowb + e] = pk;
        }
      }
    } else {
      // V: regs walk t; lane l16 = feature. 8B store per (mt,nt).
#pragma unroll
      for (int mt = 0; mt < 4; mt++) {
        int t = m0 + wr * 64 + mt * 16 + quad * 4;
        int b = t >> 11, tt = t & 2047;
#pragma unroll
        for (int nt = 0; nt < 4; nt++) {
          int ns = (n0 & 1023) + wc * 64 + nt * 16 + l16;
          int h = ns >> 6, e = ns & 63;
          size_t addr = (((size_t)b * 16 + h) * 64 + e) * 2048 + tt;
          u32x2 pk = { pkbf(acc[mt][nt][0], acc[mt][nt][1]),
                       pkbf(acc[mt][nt][2], acc[mt][nt][3]) };
          *(u32x2*)&Vt[addr] = pk;
        }
      }
    }
  }
}

// ---- flash attention v4 (R14 form — best measured): transposed S (A=K,
// B=Q); paired Q-tiles sequential; KVBLK=128. grid (bh=64, pair=8), block 512.
// Max-free softmax (S bounded, exp2 domain); K/V via global_load_lds with
// XOR-granule swizzle; cvt_pk packing; l-sum on the MFMA pipe (R11).
__global__ __launch_bounds__(512, 4) void attn(
    const u16* __restrict__ Q, const u16* __restrict__ K,
    const u16* __restrict__ Vt, u16* __restrict__ O) {
  __shared__ u16 lK[128 * 64];     // [s][e-swz] 16 KB
  __shared__ u16 lV[64 * 128];     // [e][s-swz] 16 KB
  __shared__ u16 lP[8 * 16 * 40];  // per-wave [16t][32s, stride 40]
  const int tid = threadIdx.x;
  const int lane = tid & 63, wave = tid >> 6;
  const int quad = lane >> 4, l16 = lane & 15;
  const int bh = blockIdx.x;
  const int pidx = blockIdx.y;     // 0..7
  const size_t base = (size_t)bh * (2048 * 64);
  u16* lPw = lP + wave * 640;
  const int b = bh >> 4, h = bh & 15;
  AS3 u16* lK3 = (AS3 u16*)lK;
  AS3 u16* lV3 = (AS3 u16*)lV;

  // K staging: instr (wave,i): rows wave*16+i*8+(lane>>3), src granule
  // g=(lane&7)^(lane>>3); dest linear granule (wave*2+i)*64+lane.
  const int g3 = ((lane & 7) ^ (lane >> 3)) * 8;
  const u16* gK = K + base + (size_t)(wave * 16 + (lane >> 3)) * 64 + g3;
  // V staging: instr (wave,i): row e=wave*8+i*4+(lane>>4), src granule
  // g=(lane&15)^(e&7).
  const int er = lane >> 4, p16 = lane & 15;
  const int e0 = wave * 8 + er, e1 = wave * 8 + 4 + er;
  const u16* gV0 = Vt + base + (size_t)e0 * 2048 + ((p16 ^ (e0 & 7)) * 8);
  const u16* gV1 = Vt + base + (size_t)e1 * 2048 + ((p16 ^ (e1 & 7)) * 8);

  const int e7 = l16 & 7;
  const int pq0 = (quad ^ e7) * 8;        // K read pos, e-granule quad
  const int pq1 = ((4 + quad) ^ e7) * 8;  // K read pos, e-granule 4+quad

  // ones A-frag for the l-sum MFMA (bf16 1.0 = 0x3F80)
  us8 ones_u = { 0x3F80, 0x3F80, 0x3F80, 0x3F80, 0x3F80, 0x3F80, 0x3F80, 0x3F80 };
  const bf16x8 onesA = __builtin_bit_cast(bf16x8, ones_u);

  for (int half = 0; half < 2; half++) {
    const int qb = half ? pidx : (15 - pidx);   // long tile first
    const int t0 = qb << 7;
    const int tq = t0 + wave * 16 + l16;
    const bf16x8 qF0 = ldfrag(Q + base + (size_t)tq * 64 + quad * 8);
    const bf16x8 qF1 = ldfrag(Q + base + (size_t)tq * 64 + 32 + quad * 8);
    float l_i = 0.f;
    f32x4 o[4] = {};

    for (int j = 0; j <= qb; j++) {
      const int s0 = j << 7;
      __syncthreads();
      gl_lds16(gK + (size_t)s0 * 64,       lK3 + wave * 1024);
      gl_lds16(gK + (size_t)s0 * 64 + 512, lK3 + wave * 1024 + 512);
      gl_lds16(gV0 + s0, lV3 + wave * 1024);
      gl_lds16(gV1 + s0, lV3 + wave * 1024 + 512);
      __syncthreads();

      // S^T = K·Q^T : lane owns col t=tq, rows s = nt*16+quad*4+r
      f32x4 S[8];
      __builtin_amdgcn_s_setprio(1);
#pragma unroll
      for (int nt = 0; nt < 8; nt++) {
        int sr = nt * 16 + l16;
        f32x4 a = {};
        a = mfma16(ldfrag(&lK[sr * 64 + pq0]), qF0, a);
        a = mfma16(ldfrag(&lK[sr * 64 + pq1]), qF1, a);
        S[nt] = a;
      }
      __builtin_amdgcn_s_setprio(0);

      if (j == qb) {  // causal mask on diagonal tile
#pragma unroll
        for (int nt = 0; nt < 8; nt++)
#pragma unroll
          for (int r = 0; r < 4; r++) {
            int s = s0 + nt * 16 + quad * 4 + r;
            if (s > tq) S[nt][r] = -INFINITY;
          }
      }

      // shift-free softmax numerator: P = exp2(S) (S bounded; exp2(-inf)=0)
#pragma unroll
      for (int nt = 0; nt < 8; nt++)
#pragma unroll
        for (int r = 0; r < 4; r++)
          S[nt][r] = __builtin_amdgcn_exp2f(S[nt][r]);

      // PV per 32-wide s-chunk: P^T through wave-private LDS (in-order DS).
      // l-sum rides the MFMA pipe: ol = onesA · bP accumulated per chunk.
      f32x4 ol = {};
#pragma unroll
      for (int c = 0; c < 4; c++) {
        u32x2 d0 = { cvtpk(S[2*c][0],   S[2*c][1]),   cvtpk(S[2*c][2],   S[2*c][3]) };
        u32x2 d1 = { cvtpk(S[2*c+1][0], S[2*c+1][1]), cvtpk(S[2*c+1][2], S[2*c+1][3]) };
        *(u32x2*)&lPw[l16 * 40 + quad * 4]      = d0;  // s_local = quad*4+r
        *(u32x2*)&lPw[l16 * 40 + 16 + quad * 4] = d1;  // s_local = 16+quad*4+r
        __asm__ volatile("s_waitcnt lgkmcnt(0)" ::: "memory");
        bf16x8 bP = ldfrag(&lPw[l16 * 40 + quad * 8]);  // B-frag: n=t=l16, k=quad*8+j
        __builtin_amdgcn_s_setprio(1);
#pragma unroll
        for (int ot = 0; ot < 4; ot++) {
          int pos = ((c * 4 + quad) ^ e7) * 8;  // V read: s-granule c*4+quad
          o[ot] = mfma16(ldfrag(&lV[(ot * 16 + l16) * 128 + pos]), bP, o[ot]);
        }
        ol = mfma16(onesA, bP, ol);
        __builtin_amdgcn_s_setprio(0);
      }
      l_i += ol[0];
    }

    // O^T in C-layout: row e = ot*16+quad*4+r, col t = l16 -> per-lane 8B stores
    const float inv = 1.f / l_i;
#pragma unroll
    for (int ot = 0; ot < 4; ot++) {
      u32x2 pk = { cvtpk(o[ot][0] * inv, o[ot][1] * inv),
                   cvtpk(o[ot][2] * inv, o[ot][3] * inv) };
      *(u32x2*)&O[((size_t)b * 2048 + tq) * 1024 + h * 64 + ot * 16 + quad * 4] = pk;
    }
  }
}

// ---- GEMM2: out = Ao @ Wo^T + bo, fp32 epilogue. BK=128 (R22 — KEPT here
// under test; R23 isolates its effect vs R21's BK=64). grid (8, 64), block 256.
__global__ __launch_bounds__(256) void gemm_out(
    const u16* __restrict__ A, const u16* __restrict__ W,
    const float* __restrict__ bias, float* __restrict__ out) {
  __shared__ u16 lA[128 * 128];
  __shared__ u16 lB[128 * 128];
  const int tid = threadIdx.x;
  const int lane = tid & 63, wave = tid >> 6;
  const int quad = lane >> 4, l16 = lane & 15;
  const int wr = wave >> 1, wc = wave & 1;
  const int m0 = blockIdx.y * 128;
  const int n0 = blockIdx.x * 128;
  AS3 u16* lA3 = (AS3 u16*)lA;
  AS3 u16* lB3 = (AS3 u16*)lB;
  f32x4 acc[4][4] = {};
  const int g3 = (((lane & 15) ^ ((4 * wave + quad) & 7)) * 8);
  const int srow = 4 * wave + quad;
  const int r7 = l16 & 7;
  const u16* gA = A + (size_t)(m0 + srow) * 1024 + g3;
  const u16* gB = W + (size_t)(n0 + srow) * 1024 + g3;

  for (int k0 = 0; k0 < 1024; k0 += 128) {
    __syncthreads();
#pragma unroll
    for (int i = 0; i < 8; i++) {
      gl_lds16(gA + (size_t)i * 16384 + k0, lA3 + (i * 4 + wave) * 512);
      gl_lds16(gB + (size_t)i * 16384 + k0, lB3 + (i * 4 + wave) * 512);
    }
    __syncthreads();
#pragma unroll
    for (int kk = 0; kk < 4; kk++) {
      const int pk = ((kk * 4 + quad) ^ r7) * 8;
      bf16x8 aF[4], bF[4];
#pragma unroll
      for (int mt = 0; mt < 4; mt++)
        aF[mt] = ldfrag(&lA[(wr * 64 + mt * 16 + l16) * 128 + pk]);
#pragma unroll
      for (int nt = 0; nt < 4; nt++)
        bF[nt] = ldfrag(&lB[(wc * 64 + nt * 16 + l16) * 128 + pk]);
#pragma unroll
      for (int mt = 0; mt < 4; mt++)
#pragma unroll
        for (int nt = 0; nt < 4; nt++)
          acc[mt][nt] = mfma16(aF[mt], bF[nt], acc[mt][nt]);
    }
  }

#pragma unroll
  for (int mt = 0; mt < 4; mt++) {
#pragma unroll
    for (int nt = 0; nt < 4; nt++) {
#pragma unroll
      for (int r = 0; r < 4; r++) {
        int m = m0 + wr * 64 + mt * 16 + quad * 4 + r;
        int n = n0 + wc * 64 + nt * 16 + l16;
        out[(size_t)m * 1024 + n] = acc[mt][nt][r] + bias[n];
      }
    }
  }
}

extern "C" void kernel_launch(void* const* d_in, const int* in_sizes, int n_in,
                              void* d_out, int out_size, void* d_ws, size_t ws_size,
                              hipStream_t stream) {
  const float* x  = (const float*)d_in[0];
  const float* Wq = (const float*)d_in[1];
  const float* Wk = (const float*)d_in[2];
  const float* Wv = (const float*)d_in[3];
  const float* Wo = (const float*)d_in[4];
  const float* bo = (const float*)d_in[5];
  float* out = (float*)d_out;

  // ws (u16 elems), 40 MB total: xb/Ao | Wqkv | Wob | Qb.
  // d_out doubles as scratch for Kb+Vt (dead before gemm_out's fp32 write).
  u16* ws   = (u16*)d_ws;
  u16* xb   = ws;
  u16* Wqkv = ws + 8388608;
  u16* Wob  = ws + 11534336;
  u16* Qb   = ws + 12582912;
  u16* Ao   = xb;                       // lifetime-disjoint reuse
  u16* Kb   = (u16*)d_out;
  u16* Vt   = Kb + 8388608;

  cvt_all<<<3072, 256, 0, stream>>>(x, Wq, Wk, Wv, Wo, xb, Wqkv, Wob);
  gemm_qkv<<<512, 256, 0, stream>>>(xb, Wqkv, Qb, Kb, Vt);
  attn<<<dim3(64, 8), 512, 0, stream>>>(Qb, Kb, Vt, Ao);
  gemm_out<<<dim3(8, 64), 256, 0, stream>>>(Ao, Wob, bo, out);
}

// Round 19
// 233.858 us; speedup vs baseline: 1.0200x; 1.0200x over previous
//
#include <hip/hip_runtime.h>
#include <cstdint>
#include <cstddef>

// ---- types ----
typedef unsigned short u16;
typedef float  f32x4  __attribute__((ext_vector_type(4)));
typedef __bf16 bf16x8 __attribute__((ext_vector_type(8)));
typedef unsigned short us8 __attribute__((ext_vector_type(8)));
typedef unsigned short us4 __attribute__((ext_vector_type(4)));
typedef float  f32x4v __attribute__((ext_vector_type(4)));
typedef unsigned int u32x2 __attribute__((ext_vector_type(2)));

#define AS1 __attribute__((address_space(1)))
#define AS3 __attribute__((address_space(3)))

// fp32 -> bf16 round-to-nearest-even (scalar)
__device__ __forceinline__ u16 f2b(float f) {
  unsigned u = __float_as_uint(f);
  u += 0x7FFFu + ((u >> 16) & 1u);
  return (u16)(u >> 16);
}

// pack two fp32 -> bf16x2 dword (round-half-up; a = low 16, b = high 16)
__device__ __forceinline__ unsigned pkbf(float a, float b) {
  unsigned ua = __float_as_uint(a) + 0x8000u;
  unsigned ub = __float_as_uint(b) + 0x8000u;
  return __builtin_amdgcn_perm(ub, ua, 0x07060302u);
}

// pack two fp32 -> bf16x2 via casts (compiler emits v_cvt_pk_bf16_f32, RNE)
__device__ __forceinline__ unsigned cvtpk(float a, float b) {
  unsigned short lo = __builtin_bit_cast(unsigned short, (__bf16)a);
  unsigned short hi = __builtin_bit_cast(unsigned short, (__bf16)b);
  return (unsigned)lo | ((unsigned)hi << 16);
}

__device__ __forceinline__ bf16x8 ldfrag(const u16* p) {
  us8 v = *(const us8*)p;
  return __builtin_bit_cast(bf16x8, v);
}

__device__ __forceinline__ f32x4 mfma16(bf16x8 a, bf16x8 b, f32x4 c) {
  return __builtin_amdgcn_mfma_f32_16x16x32_bf16(a, b, c, 0, 0, 0);
}

// async global->LDS, 16B per lane; lds base must be wave-uniform (lane*16 auto-added)
__device__ __forceinline__ void gl_lds16(const u16* g, AS3 u16* l) {
  __builtin_amdgcn_global_load_lds((AS1 void*)g, (AS3 void*)l, 16, 0, 0);
}

// R13 BK=64 LDS layout (proven conflict-free): rows of 64 u16 = eight 16B
// granules; row stride 128B. LDS[r][p] = global[r][g], p = g^(r&7). Staging
// source granule g = (lane&7)^(lane>>3); reader pos = (kk*4+quad)^(l16&7).
// Measured 0 bank conflicts.
// R24 (gemm_qkv): BK=128 via TWO independent BK=64 sub-chunks, each using
// the byte-identical proven layout (zero new swizzle math — R22's unified
// 16-granule layout measured 6.29e6 conflicts and is abandoned). One barrier
// region stages both chunks (16 gl_lds/thread); 64 MFMA per drain; barrier
// pairs 48 -> 24. Decides: drain fixed-latency (win) vs throughput-bound
// (null -> structural floor).
// R23: gemm_out BK=128 was noise-or-worse -> reverted to BK=64.
// R25 = R24 resubmitted verbatim (container-acquisition failure, unmeasured).

// ---- fused cast: x + all 4 weights. grid-stride, 3072 blocks x 4 iters ----
__global__ __launch_bounds__(256) void cvt_all(
    const float* __restrict__ x,
    const float* __restrict__ Wq, const float* __restrict__ Wk,
    const float* __restrict__ Wv, const float* __restrict__ Wo,
    u16* __restrict__ xb, u16* __restrict__ Wqkv, u16* __restrict__ Wob) {
  for (int blk = blockIdx.x; blk < 12288; blk += 3072) {
    const float* s;
    u16* d;
    int i;
    if (blk < 8192)       { s = x;  d = xb;             i = blk * 256 + threadIdx.x; }
    else if (blk < 9216)  { s = Wq; d = Wqkv;           i = (blk - 8192) * 256 + threadIdx.x; }
    else if (blk < 10240) { s = Wk; d = Wqkv + 1048576; i = (blk - 9216) * 256 + threadIdx.x; }
    else if (blk < 11264) { s = Wv; d = Wqkv + 2097152; i = (blk - 10240) * 256 + threadIdx.x; }
    else                  { s = Wo; d = Wob;            i = (blk - 11264) * 256 + threadIdx.x; }
    f32x4v f = ((const f32x4v*)s)[i];
    us4 o = { f2b(f[0]), f2b(f[1]), f2b(f[2]), f2b(f[3]) };
    ((us4*)d)[i] = o;
  }
}

// ---- GEMM1: C = X @ Wqkv^T -> Q (prescaled by 0.125*log2e), K, Vt.
// 128x128 tile, 256 threads, dual-chunk BK=128 (R24), per-section MFMA
// orientation + 8B packed epilogue (R12), persistent 512-block grid +
// same-A sec fusion + 1-D XCD chunk (R15). Serial-stage 2-barrier loop.
__global__ __launch_bounds__(256) void gemm_qkv(
    const u16* __restrict__ A, const u16* __restrict__ W,
    u16* __restrict__ Qb, u16* __restrict__ Kb, u16* __restrict__ Vt) {
  __shared__ u16 lA[2 * 128 * 64];   // 32 KB: two proven BK=64 sub-chunks
  __shared__ u16 lB[2 * 128 * 64];   // 32 KB
  const int tid = threadIdx.x;
  const int lane = tid & 63, wave = tid >> 6;
  const int quad = lane >> 4, l16 = lane & 15;
  const int wr = wave >> 1, wc = wave & 1;

  const int p = blockIdx.x;
  const int l = (p & 7) * 64 + (p >> 3);   // XCD-chunk swizzle (bijective)
  const int by = l >> 3;
  const int bx0 = l & 7;
  const int m0 = by * 128;

  AS3 u16* lA3 = (AS3 u16*)lA;
  AS3 u16* lB3 = (AS3 u16*)lB;
  const int g3 = (((lane & 7) ^ (lane >> 3)) * 8);   // staging source granule col
  const int srow = lane >> 3;                        // 0..7 within 8-row group
  const int pA = ((quad) ^ (l16 & 7)) * 8;           // reader pos, kk=0
  const int pB = ((4 + quad) ^ (l16 & 7)) * 8;       // reader pos, kk=1

  const u16* gA = A + (size_t)(m0 + wave * 8 + srow) * 1024 + g3;

#pragma unroll 1
  for (int sec = 0; sec < 3; sec++) {    // tile bx = bx0 + sec*8; sec: 0=Q 1=K 2=V
    const int n0 = (bx0 + sec * 8) * 128;
    const u16* gB = W + (size_t)(n0 + wave * 8 + srow) * 1024 + g3;
    f32x4 acc[4][4] = {};

    for (int k0 = 0; k0 < 1024; k0 += 128) {
      __syncthreads();
#pragma unroll
      for (int c = 0; c < 2; c++) {   // chunk c covers k in [k0+64c, k0+64c+64)
#pragma unroll
        for (int i = 0; i < 4; i++) { // instr (i,wave) stages rows (i*4+wave)*8..+7
          gl_lds16(gA + (size_t)i * 32768 + k0 + c * 64,
                   lA3 + c * 8192 + (i * 4 + wave) * 512);
          gl_lds16(gB + (size_t)i * 32768 + k0 + c * 64,
                   lB3 + c * 8192 + (i * 4 + wave) * 512);
        }
      }
      __syncthreads();
#pragma unroll
      for (int c = 0; c < 2; c++) {
        const u16* bAp = lA + c * 8192;
        const u16* bBp = lB + c * 8192;
#pragma unroll
        for (int kk = 0; kk < 2; kk++) {
          const int pk = kk ? pB : pA;
          bf16x8 aF[4], bF[4];
#pragma unroll
          for (int mt = 0; mt < 4; mt++)
            aF[mt] = ldfrag(&bAp[(wr * 64 + mt * 16 + l16) * 64 + pk]);
#pragma unroll
          for (int nt = 0; nt < 4; nt++)
            bF[nt] = ldfrag(&bBp[(wc * 64 + nt * 16 + l16) * 64 + pk]);
          if (sec != 2) {  // SWAPPED: D[row=feature n, col=token m]
#pragma unroll
            for (int mt = 0; mt < 4; mt++)
#pragma unroll
              for (int nt = 0; nt < 4; nt++)
                acc[mt][nt] = mfma16(bF[nt], aF[mt], acc[mt][nt]);
          } else {         // NON-swapped: D[row=token m, col=feature n]
#pragma unroll
            for (int mt = 0; mt < 4; mt++)
#pragma unroll
              for (int nt = 0; nt < 4; nt++)
                acc[mt][nt] = mfma16(aF[mt], bF[nt], acc[mt][nt]);
          }
        }
      }
    }

    if (sec != 2) {
      // Q/K: regs walk e; lane l16 = token. 8B store per (mt,nt).
      const float qsc = (sec == 0) ? 0.180336880111120426f : 1.0f;  // 0.125*log2e
      u16* __restrict__ D = (sec == 0) ? Qb : Kb;
      const int hb = ((n0 & 1023) >> 6) + wc;  // head (uniform per wave-col)
#pragma unroll
      for (int mt = 0; mt < 4; mt++) {
        int t = m0 + wr * 64 + mt * 16 + l16;
        int b = t >> 11, tt = t & 2047;
        size_t rowb = (((size_t)b * 16 + hb) * 2048 + tt) * 64;
#pragma unroll
        for (int nt = 0; nt < 4; nt++) {
          int e = nt * 16 + quad * 4;
          u32x2 pk = { pkbf(acc[mt][nt][0] * qsc, acc[mt][nt][1] * qsc),
                       pkbf(acc[mt][nt][2] * qsc, acc[mt][nt][3] * qsc) };
          *(u32x2*)&D[rowb + e] = pk;
        }
      }
    } else {
      // V: regs walk t; lane l16 = feature. 8B store per (mt,nt).
#pragma unroll
      for (int mt = 0; mt < 4; mt++) {
        int t = m0 + wr * 64 + mt * 16 + quad * 4;
        int b = t >> 11, tt = t & 2047;
#pragma unroll
        for (int nt = 0; nt < 4; nt++) {
          int ns = (n0 & 1023) + wc * 64 + nt * 16 + l16;
          int h = ns >> 6, e = ns & 63;
          size_t addr = (((size_t)b * 16 + h) * 64 + e) * 2048 + tt;
          u32x2 pk = { pkbf(acc[mt][nt][0], acc[mt][nt][1]),
                       pkbf(acc[mt][nt][2], acc[mt][nt][3]) };
          *(u32x2*)&Vt[addr] = pk;
        }
      }
    }
  }
}

// ---- flash attention v4 (R14 form — best measured): transposed S (A=K,
// B=Q); paired Q-tiles sequential; KVBLK=128. grid (bh=64, pair=8), block 512.
// Max-free softmax (S bounded, exp2 domain); K/V via global_load_lds with
// XOR-granule swizzle; cvt_pk packing; l-sum on the MFMA pipe (R11).
__global__ __launch_bounds__(512, 4) void attn(
    const u16* __restrict__ Q, const u16* __restrict__ K,
    const u16* __restrict__ Vt, u16* __restrict__ O) {
  __shared__ u16 lK[128 * 64];     // [s][e-swz] 16 KB
  __shared__ u16 lV[64 * 128];     // [e][s-swz] 16 KB
  __shared__ u16 lP[8 * 16 * 40];  // per-wave [16t][32s, stride 40]
  const int tid = threadIdx.x;
  const int lane = tid & 63, wave = tid >> 6;
  const int quad = lane >> 4, l16 = lane & 15;
  const int bh = blockIdx.x;
  const int pidx = blockIdx.y;     // 0..7
  const size_t base = (size_t)bh * (2048 * 64);
  u16* lPw = lP + wave * 640;
  const int b = bh >> 4, h = bh & 15;
  AS3 u16* lK3 = (AS3 u16*)lK;
  AS3 u16* lV3 = (AS3 u16*)lV;

  // K staging: instr (wave,i): rows wave*16+i*8+(lane>>3), src granule
  // g=(lane&7)^(lane>>3); dest linear granule (wave*2+i)*64+lane.
  const int g3 = ((lane & 7) ^ (lane >> 3)) * 8;
  const u16* gK = K + base + (size_t)(wave * 16 + (lane >> 3)) * 64 + g3;
  // V staging: instr (wave,i): row e=wave*8+i*4+(lane>>4), src granule
  // g=(lane&15)^(e&7).
  const int er = lane >> 4, p16 = lane & 15;
  const int e0 = wave * 8 + er, e1 = wave * 8 + 4 + er;
  const u16* gV0 = Vt + base + (size_t)e0 * 2048 + ((p16 ^ (e0 & 7)) * 8);
  const u16* gV1 = Vt + base + (size_t)e1 * 2048 + ((p16 ^ (e1 & 7)) * 8);

  const int e7 = l16 & 7;
  const int pq0 = (quad ^ e7) * 8;        // K read pos, e-granule quad
  const int pq1 = ((4 + quad) ^ e7) * 8;  // K read pos, e-granule 4+quad

  // ones A-frag for the l-sum MFMA (bf16 1.0 = 0x3F80)
  us8 ones_u = { 0x3F80, 0x3F80, 0x3F80, 0x3F80, 0x3F80, 0x3F80, 0x3F80, 0x3F80 };
  const bf16x8 onesA = __builtin_bit_cast(bf16x8, ones_u);

  for (int half = 0; half < 2; half++) {
    const int qb = half ? pidx : (15 - pidx);   // long tile first
    const int t0 = qb << 7;
    const int tq = t0 + wave * 16 + l16;
    const bf16x8 qF0 = ldfrag(Q + base + (size_t)tq * 64 + quad * 8);
    const bf16x8 qF1 = ldfrag(Q + base + (size_t)tq * 64 + 32 + quad * 8);
    float l_i = 0.f;
    f32x4 o[4] = {};

    for (int j = 0; j <= qb; j++) {
      const int s0 = j << 7;
      __syncthreads();
      gl_lds16(gK + (size_t)s0 * 64,       lK3 + wave * 1024);
      gl_lds16(gK + (size_t)s0 * 64 + 512, lK3 + wave * 1024 + 512);
      gl_lds16(gV0 + s0, lV3 + wave * 1024);
      gl_lds16(gV1 + s0, lV3 + wave * 1024 + 512);
      __syncthreads();

      // S^T = K·Q^T : lane owns col t=tq, rows s = nt*16+quad*4+r
      f32x4 S[8];
      __builtin_amdgcn_s_setprio(1);
#pragma unroll
      for (int nt = 0; nt < 8; nt++) {
        int sr = nt * 16 + l16;
        f32x4 a = {};
        a = mfma16(ldfrag(&lK[sr * 64 + pq0]), qF0, a);
        a = mfma16(ldfrag(&lK[sr * 64 + pq1]), qF1, a);
        S[nt] = a;
      }
      __builtin_amdgcn_s_setprio(0);

      if (j == qb) {  // causal mask on diagonal tile
#pragma unroll
        for (int nt = 0; nt < 8; nt++)
#pragma unroll
          for (int r = 0; r < 4; r++) {
            int s = s0 + nt * 16 + quad * 4 + r;
            if (s > tq) S[nt][r] = -INFINITY;
          }
      }

      // shift-free softmax numerator: P = exp2(S) (S bounded; exp2(-inf)=0)
#pragma unroll
      for (int nt = 0; nt < 8; nt++)
#pragma unroll
        for (int r = 0; r < 4; r++)
          S[nt][r] = __builtin_amdgcn_exp2f(S[nt][r]);

      // PV per 32-wide s-chunk: P^T through wave-private LDS (in-order DS).
      // l-sum rides the MFMA pipe: ol = onesA · bP accumulated per chunk.
      f32x4 ol = {};
#pragma unroll
      for (int c = 0; c < 4; c++) {
        u32x2 d0 = { cvtpk(S[2*c][0],   S[2*c][1]),   cvtpk(S[2*c][2],   S[2*c][3]) };
        u32x2 d1 = { cvtpk(S[2*c+1][0], S[2*c+1][1]), cvtpk(S[2*c+1][2], S[2*c+1][3]) };
        *(u32x2*)&lPw[l16 * 40 + quad * 4]      = d0;  // s_local = quad*4+r
        *(u32x2*)&lPw[l16 * 40 + 16 + quad * 4] = d1;  // s_local = 16+quad*4+r
        __asm__ volatile("s_waitcnt lgkmcnt(0)" ::: "memory");
        bf16x8 bP = ldfrag(&lPw[l16 * 40 + quad * 8]);  // B-frag: n=t=l16, k=quad*8+j
        __builtin_amdgcn_s_setprio(1);
#pragma unroll
        for (int ot = 0; ot < 4; ot++) {
          int pos = ((c * 4 + quad) ^ e7) * 8;  // V read: s-granule c*4+quad
          o[ot] = mfma16(ldfrag(&lV[(ot * 16 + l16) * 128 + pos]), bP, o[ot]);
        }
        ol = mfma16(onesA, bP, ol);
        __builtin_amdgcn_s_setprio(0);
      }
      l_i += ol[0];
    }

    // O^T in C-layout: row e = ot*16+quad*4+r, col t = l16 -> per-lane 8B stores
    const float inv = 1.f / l_i;
#pragma unroll
    for (int ot = 0; ot < 4; ot++) {
      u32x2 pk = { cvtpk(o[ot][0] * inv, o[ot][1] * inv),
                   cvtpk(o[ot][2] * inv, o[ot][3] * inv) };
      *(u32x2*)&O[((size_t)b * 2048 + tq) * 1024 + h * 64 + ot * 16 + quad * 4] = pk;
    }
  }
}

// ---- GEMM2: out = Ao @ Wo^T + bo, fp32 epilogue. BK=64 serial (R13/R21 —
// R23 showed BK=128 here was noise-or-worse). grid (8, 64), block 256.
__global__ __launch_bounds__(256) void gemm_out(
    const u16* __restrict__ A, const u16* __restrict__ W,
    const float* __restrict__ bias, float* __restrict__ out) {
  __shared__ u16 lA[128 * 64];
  __shared__ u16 lB[128 * 64];
  const int tid = threadIdx.x;
  const int lane = tid & 63, wave = tid >> 6;
  const int quad = lane >> 4, l16 = lane & 15;
  const int wr = wave >> 1, wc = wave & 1;
  const int m0 = blockIdx.y * 128;
  const int n0 = blockIdx.x * 128;
  AS3 u16* lA3 = (AS3 u16*)lA;
  AS3 u16* lB3 = (AS3 u16*)lB;
  f32x4 acc[4][4] = {};
  const int g3 = (((lane & 7) ^ (lane >> 3)) * 8);
  const int srow = lane >> 3;
  const int pA = ((quad) ^ (l16 & 7)) * 8;
  const int pB = ((4 + quad) ^ (l16 & 7)) * 8;
  const u16* gA = A + (size_t)(m0 + wave * 8 + srow) * 1024 + g3;
  const u16* gB = W + (size_t)(n0 + wave * 8 + srow) * 1024 + g3;

  for (int k0 = 0; k0 < 1024; k0 += 64) {
    __syncthreads();
#pragma unroll
    for (int i = 0; i < 4; i++) {
      gl_lds16(gA + (size_t)i * 32768 + k0, lA3 + (i * 4 + wave) * 512);
      gl_lds16(gB + (size_t)i * 32768 + k0, lB3 + (i * 4 + wave) * 512);
    }
    __syncthreads();
#pragma unroll
    for (int kk = 0; kk < 2; kk++) {
      const int pk = kk ? pB : pA;
      bf16x8 aF[4], bF[4];
#pragma unroll
      for (int mt = 0; mt < 4; mt++)
        aF[mt] = ldfrag(&lA[(wr * 64 + mt * 16 + l16) * 64 + pk]);
#pragma unroll
      for (int nt = 0; nt < 4; nt++)
        bF[nt] = ldfrag(&lB[(wc * 64 + nt * 16 + l16) * 64 + pk]);
#pragma unroll
      for (int mt = 0; mt < 4; mt++)
#pragma unroll
        for (int nt = 0; nt < 4; nt++)
          acc[mt][nt] = mfma16(aF[mt], bF[nt], acc[mt][nt]);
    }
  }

#pragma unroll
  for (int mt = 0; mt < 4; mt++) {
#pragma unroll
    for (int nt = 0; nt < 4; nt++) {
#pragma unroll
      for (int r = 0; r < 4; r++) {
        int m = m0 + wr * 64 + mt * 16 + quad * 4 + r;
        int n = n0 + wc * 64 + nt * 16 + l16;
        out[(size_t)m * 1024 + n] = acc[mt][nt][r] + bias[n];
      }
    }
  }
}

extern "C" void kernel_launch(void* const* d_in, const int* in_sizes, int n_in,
                              void* d_out, int out_size, void* d_ws, size_t ws_size,
                              hipStream_t stream) {
  const float* x  = (const float*)d_in[0];
  const float* Wq = (const float*)d_in[1];
  const float* Wk = (const float*)d_in[2];
  const float* Wv = (const float*)d_in[3];
  const float* Wo = (const float*)d_in[4];
  const float* bo = (const float*)d_in[5];
  float* out = (float*)d_out;

  // ws (u16 elems), 40 MB total: xb/Ao | Wqkv | Wob | Qb.
  // d_out doubles as scratch for Kb+Vt (dead before gemm_out's fp32 write).
  u16* ws   = (u16*)d_ws;
  u16* xb   = ws;
  u16* Wqkv = ws + 8388608;
  u16* Wob  = ws + 11534336;
  u16* Qb   = ws + 12582912;
  u16* Ao   = xb;                       // lifetime-disjoint reuse
  u16* Kb   = (u16*)d_out;
  u16* Vt   = Kb + 8388608;

  cvt_all<<<3072, 256, 0, stream>>>(x, Wq, Wk, Wv, Wo, xb, Wqkv, Wob);
  gemm_qkv<<<512, 256, 0, stream>>>(xb, Wqkv, Qb, Kb, Vt);
  attn<<<dim3(64, 8), 512, 0, stream>>>(Qb, Kb, Vt, Ao);
  gemm_out<<<dim3(8, 64), 256, 0, stream>>>(Ao, Wob, bo, out);
}